// Round 8
// baseline (743.614 us; speedup 1.0000x reference)
//
#include <hip/hip_runtime.h>
#include <hip/hip_bf16.h>
#include <hip/hip_fp16.h>
#include <hip/hip_cooperative_groups.h>

namespace cg = cooperative_groups;

#define EMB 16
#define EPT 4    // edges per 16-lane group (fallback kernels, proven shape)
#define FEPT 8   // edges per group in fused kernel (2x in-flight gathers to
                 // compensate cooperative occupancy 27 -> ~16-20 waves/CU)

typedef _Float16 half8 __attribute__((ext_vector_type(8)));
typedef _Float16 half2v __attribute__((ext_vector_type(2)));

#if defined(__has_builtin)
#if __has_builtin(__builtin_amdgcn_fdot2)
#define HAS_FDOT2 1
#endif
#endif

union U32H2 { int i; half2v h; };

struct FArgs {
    const float* left; const float* ef; const float* right; const int* idx;
    const float* Wl; const float* bl; const float* Wedge; const float* Wr;
    const float* Wf; const float* bf; const float* Wp; const float* bp;
    const float* Wo1; const float* bo1; const float* Wo2; const float* bo2;
    _Float16* TL; _Float16* TR; _Float16* S16; float* out;
    int NL, NR, E, G;
};

// ---------------------------------------------------------------------------
// Fused cooperative kernel: P0 (zero S + node transforms) -> grid.sync ->
// P1 (edge scatter, R7's proven body, grid-stride, FEPT=8) -> grid.sync ->
// P2 (epilogue). Eliminates 3 inter-kernel gaps + the memset dispatch.
// ---------------------------------------------------------------------------
__global__ __launch_bounds__(256, 4) void fused_kernel(FArgs a) {
    cg::grid_group grid = cg::this_grid();
    const int tid = threadIdx.x;
    const int gtid = blockIdx.x * 256 + tid;
    const int nthreads = gridDim.x * 256;

    __shared__ float sWl[256], sWr[256], sbl[16];
    __shared__ float sWp[256], sWo2[256], sWo1[512];
    __shared__ float sbp[16], sbo1[16], sbo2[16];

    // ---- P0a: zero the scatter accumulator S (NR*2 uint4 rows) ----------
    {
        uint4* Sz = (uint4*)a.S16;
        const uint4 z = make_uint4(0u, 0u, 0u, 0u);
        int n4 = a.NR * 2;
        for (int i = gtid; i < n4; i += nthreads) Sz[i] = z;
    }

    // ---- P0b: node transforms (proven body, grid-stride) -----------------
    if (tid < 256) { sWl[tid] = a.Wl[tid]; sWr[tid] = a.Wr[tid]; }
    if (tid < 16) sbl[tid] = a.bl[tid];
    __syncthreads();

    for (int n = gtid; n < a.NL + a.NR; n += nthreads) {
        bool is_left = (n < a.NL);
        const float* X = is_left ? (a.left + (size_t)n * EMB)
                                 : (a.right + (size_t)(n - a.NL) * EMB);
        _Float16* Y = is_left ? (a.TL + (size_t)n * EMB)
                              : (a.TR + (size_t)(n - a.NL) * EMB);
        const float* sW = is_left ? sWl : sWr;

        float x[EMB];
        const float4* xp = (const float4*)X;
        float4 x0 = xp[0], x1 = xp[1], x2 = xp[2], x3 = xp[3];
        x[0] = x0.x; x[1] = x0.y; x[2] = x0.z; x[3] = x0.w;
        x[4] = x1.x; x[5] = x1.y; x[6] = x1.z; x[7] = x1.w;
        x[8] = x2.x; x[9] = x2.y; x[10] = x2.z; x[11] = x2.w;
        x[12] = x3.x; x[13] = x3.y; x[14] = x3.z; x[15] = x3.w;

        float y[EMB];
#pragma unroll
        for (int j = 0; j < EMB; ++j) {
            float acc = is_left ? sbl[j] : 0.0f;
#pragma unroll
            for (int k = 0; k < EMB; ++k) acc = fmaf(sW[j * EMB + k], x[k], acc);
            y[j] = acc;
        }
        half8 h0, h1;
#pragma unroll
        for (int k = 0; k < 8; ++k) h0[k] = (_Float16)y[k];
#pragma unroll
        for (int k = 0; k < 8; ++k) h1[k] = (_Float16)y[8 + k];
        ((half8*)Y)[0] = h0;
        ((half8*)Y)[1] = h1;
    }

    grid.sync();

    // ---- P1: edge scatter (R7 body, grid-stride over groups, FEPT=8) -----
    {
        const int t = tid & 15;
        const int lane = tid & 63;
        const int gbase = lane & 48;
        const int bp0 = (gbase | ((2 * t) & 15)) << 2;
        const int bp1 = (gbase | ((2 * t + 1) & 15)) << 2;

        const float we = a.Wedge[t];
        const float bft = a.bf[t];
        half2v wpk[8];
        {
            const float* wr = a.Wf + t * EMB;
#pragma unroll
            for (int k = 0; k < 8; ++k) {
                wpk[k][0] = (_Float16)wr[2 * k];
                wpk[k][1] = (_Float16)wr[2 * k + 1];
            }
        }
        const bool odd = (t & 1);
        const int G = a.G;                 // = ceil(E / FEPT)
        const int NG = nthreads >> 4;
        __half2* S = (__half2*)a.S16;

        for (int g = gtid >> 4; g < G; g += NG) {
            int l[FEPT], r[FEPT];
            float efv[FEPT];
            bool valid[FEPT];
#pragma unroll
            for (int j = 0; j < FEPT; ++j) {
                int e = g + j * G;
                valid[j] = (e < a.E);
                int ec = valid[j] ? e : 0;
                l[j] = a.idx[ec];
                r[j] = a.idx[a.E + ec];
                efv[j] = a.ef[ec];
            }
            _Float16 ah[FEPT], bh[FEPT];
#pragma unroll
            for (int j = 0; j < FEPT; ++j) {
                ah[j] = a.TL[(size_t)l[j] * EMB + t];
                bh[j] = a.TR[(size_t)r[j] * EMB + t];
            }
#pragma unroll
            for (int j = 0; j < FEPT; ++j) {
                float v = fmaxf((float)ah[j] + (float)bh[j] + efv[j] * we, 0.0f);

                int hvi = (int)__half_as_ushort(__float2half(v));
                int hxi = __builtin_amdgcn_ds_swizzle(hvi, 0x041F);   // lane^1
                int lo = odd ? hxi : hvi;
                int hi = odd ? hvi : hxi;
                int pk = (lo & 0xFFFF) | (hi << 16);

                float w = bft;
#define DOT_STEP(K)                                                           \
                {                                                             \
                    U32H2 u;                                                  \
                    u.i = __builtin_amdgcn_ds_swizzle(                        \
                        pk, ((2 * (K)) << 5) | 0x10);                         \
                    DOT_BODY(K)                                               \
                }
#if defined(HAS_FDOT2)
#define DOT_BODY(K) w = __builtin_amdgcn_fdot2(u.h, wpk[K], w, false);
#else
#define DOT_BODY(K)                                                           \
                    w = fmaf((float)u.h[0], (float)wpk[K][0], w);             \
                    w = fmaf((float)u.h[1], (float)wpk[K][1], w);
#endif
                DOT_STEP(0) DOT_STEP(1) DOT_STEP(2) DOT_STEP(3)
                DOT_STEP(4) DOT_STEP(5) DOT_STEP(6) DOT_STEP(7)
#undef DOT_STEP
#undef DOT_BODY

                int wi = __float_as_int(w);
                float w0 = __int_as_float(__builtin_amdgcn_ds_bpermute(bp0, wi));
                float w1 = __int_as_float(__builtin_amdgcn_ds_bpermute(bp1, wi));
                if (valid[j] && t < 8) {
                    __half2 hv = __floats2half2_rn(w0, w1);
                    unsafeAtomicAdd(S + (size_t)r[j] * 8 + t, hv);
                }
            }
        }
    }

    grid.sync();

    // ---- P2: epilogue (proven body, grid-stride) --------------------------
    for (int i = tid; i < 256; i += 256) { sWp[i] = a.Wp[i]; sWo2[i] = a.Wo2[i]; }
    for (int i = tid; i < 512; i += 256) sWo1[i] = a.Wo1[i];
    if (tid < 16) {
        sbp[tid] = a.bp[tid]; sbo1[tid] = a.bo1[tid]; sbo2[tid] = a.bo2[tid];
    }
    __syncthreads();

    for (int n = gtid; n < a.NR; n += nthreads) {
        float ra[EMB];
        {
            const half8* sp = (const half8*)(a.S16 + (size_t)n * EMB);
            half8 a0 = sp[0], a1 = sp[1];
#pragma unroll
            for (int k = 0; k < 8; ++k) ra[k] = fmaxf((float)a0[k], 0.0f);
#pragma unroll
            for (int k = 0; k < 8; ++k) ra[8 + k] = fmaxf((float)a1[k], 0.0f);
        }
        float p[EMB];
#pragma unroll
        for (int j = 0; j < EMB; ++j) {
            float acc = sbp[j];
#pragma unroll
            for (int k = 0; k < EMB; ++k) acc = fmaf(sWp[j * EMB + k], ra[k], acc);
            p[j] = acc;
        }
        float rf[EMB];
        {
            const float4* rp = (const float4*)(a.right + (size_t)n * EMB);
            float4 a0 = rp[0], a1 = rp[1], a2 = rp[2], a3 = rp[3];
            rf[0] = a0.x; rf[1] = a0.y; rf[2] = a0.z; rf[3] = a0.w;
            rf[4] = a1.x; rf[5] = a1.y; rf[6] = a1.z; rf[7] = a1.w;
            rf[8] = a2.x; rf[9] = a2.y; rf[10] = a2.z; rf[11] = a2.w;
            rf[12] = a3.x; rf[13] = a3.y; rf[14] = a3.z; rf[15] = a3.w;
        }
        float h[EMB];
#pragma unroll
        for (int j = 0; j < EMB; ++j) {
            float acc = sbo1[j];
#pragma unroll
            for (int k = 0; k < EMB; ++k) acc = fmaf(sWo1[j * 32 + k], p[k], acc);
#pragma unroll
            for (int k = 0; k < EMB; ++k)
                acc = fmaf(sWo1[j * 32 + 16 + k], rf[k], acc);
            h[j] = fmaxf(acc, 0.0f);
        }
        float o[EMB];
#pragma unroll
        for (int j = 0; j < EMB; ++j) {
            float acc = sbo2[j];
#pragma unroll
            for (int k = 0; k < EMB; ++k) acc = fmaf(sWo2[j * EMB + k], h[k], acc);
            o[j] = acc;
        }
        float4* op = (float4*)(a.out + (size_t)n * EMB);
        op[0] = make_float4(o[0], o[1], o[2], o[3]);
        op[1] = make_float4(o[4], o[5], o[6], o[7]);
        op[2] = make_float4(o[8], o[9], o[10], o[11]);
        op[3] = make_float4(o[12], o[13], o[14], o[15]);
    }
}

// ===========================================================================
// Fallback path: the R7 4-kernel sequence (proven 353.9us), used only if the
// cooperative launch is rejected at capture time.
// ===========================================================================
__global__ __launch_bounds__(256) void node_transform2_kernel(
    const float* __restrict__ left, const float* __restrict__ right,
    const float* __restrict__ Wl, const float* __restrict__ bl,
    const float* __restrict__ Wr,
    _Float16* __restrict__ TL, _Float16* __restrict__ TR, int NL, int NR) {
    __shared__ float sWl[EMB * EMB], sWr[EMB * EMB], sbl[EMB];
    if (threadIdx.x < EMB * EMB) {
        sWl[threadIdx.x] = Wl[threadIdx.x];
        sWr[threadIdx.x] = Wr[threadIdx.x];
    }
    if (threadIdx.x < EMB) sbl[threadIdx.x] = bl[threadIdx.x];
    __syncthreads();

    int n = blockIdx.x * blockDim.x + threadIdx.x;
    if (n >= NL + NR) return;
    bool is_left = (n < NL);
    const float* X = is_left ? (left + (size_t)n * EMB)
                             : (right + (size_t)(n - NL) * EMB);
    _Float16* Y = is_left ? (TL + (size_t)n * EMB)
                          : (TR + (size_t)(n - NL) * EMB);
    const float* sW = is_left ? sWl : sWr;

    float x[EMB];
    const float4* xp = (const float4*)X;
    float4 x0 = xp[0], x1 = xp[1], x2 = xp[2], x3 = xp[3];
    x[0] = x0.x; x[1] = x0.y; x[2] = x0.z; x[3] = x0.w;
    x[4] = x1.x; x[5] = x1.y; x[6] = x1.z; x[7] = x1.w;
    x[8] = x2.x; x[9] = x2.y; x[10] = x2.z; x[11] = x2.w;
    x[12] = x3.x; x[13] = x3.y; x[14] = x3.z; x[15] = x3.w;

    float y[EMB];
#pragma unroll
    for (int j = 0; j < EMB; ++j) {
        float a = is_left ? sbl[j] : 0.0f;
#pragma unroll
        for (int k = 0; k < EMB; ++k) a = fmaf(sW[j * EMB + k], x[k], a);
        y[j] = a;
    }

    half8* yp = (half8*)Y;
    half8 h0, h1;
#pragma unroll
    for (int k = 0; k < 8; ++k) h0[k] = (_Float16)y[k];
#pragma unroll
    for (int k = 0; k < 8; ++k) h1[k] = (_Float16)y[8 + k];
    yp[0] = h0;
    yp[1] = h1;
}

__global__ __launch_bounds__(256) void edge_scatter_kernel(
    const int* __restrict__ idx, const float* __restrict__ ef,
    const _Float16* __restrict__ TL, const _Float16* __restrict__ TR,
    const float* __restrict__ wedge, const float* __restrict__ Wf,
    const float* __restrict__ bf, __half2* __restrict__ S, int E, int G) {
    int gid = blockIdx.x * blockDim.x + threadIdx.x;
    int g = gid >> 4;
    int t = gid & 15;

    int lane = threadIdx.x & 63;
    int gbase = lane & 48;
    int bp0 = (gbase | ((2 * t) & 15)) << 2;
    int bp1 = (gbase | ((2 * t + 1) & 15)) << 2;

    float we = wedge[t];
    float bft = bf[t];
    half2v wpk[8];
    {
        const float* wr = Wf + t * EMB;
#pragma unroll
        for (int k = 0; k < 8; ++k) {
            wpk[k][0] = (_Float16)wr[2 * k];
            wpk[k][1] = (_Float16)wr[2 * k + 1];
        }
    }

    int l[EPT], r[EPT];
    float efv[EPT];
    bool valid[EPT];
#pragma unroll
    for (int j = 0; j < EPT; ++j) {
        int e = g + j * G;
        valid[j] = (e < E);
        int ec = valid[j] ? e : 0;
        l[j] = idx[ec];
        r[j] = idx[E + ec];
        efv[j] = ef[ec];
    }

    _Float16 ah[EPT], bh[EPT];
#pragma unroll
    for (int j = 0; j < EPT; ++j) {
        ah[j] = TL[(size_t)l[j] * EMB + t];
        bh[j] = TR[(size_t)r[j] * EMB + t];
    }

    const bool odd = (t & 1);

#pragma unroll
    for (int j = 0; j < EPT; ++j) {
        float v = fmaxf((float)ah[j] + (float)bh[j] + efv[j] * we, 0.0f);
        int hvi = (int)__half_as_ushort(__float2half(v));
        int hxi = __builtin_amdgcn_ds_swizzle(hvi, 0x041F);
        int lo = odd ? hxi : hvi;
        int hi = odd ? hvi : hxi;
        int pk = (lo & 0xFFFF) | (hi << 16);

        float w = bft;
#define DOT_STEP(K)                                                           \
        {                                                                     \
            U32H2 u;                                                          \
            u.i = __builtin_amdgcn_ds_swizzle(pk, ((2 * (K)) << 5) | 0x10);   \
            DOT_BODY(K)                                                       \
        }
#if defined(HAS_FDOT2)
#define DOT_BODY(K) w = __builtin_amdgcn_fdot2(u.h, wpk[K], w, false);
#else
#define DOT_BODY(K)                                                           \
            w = fmaf((float)u.h[0], (float)wpk[K][0], w);                     \
            w = fmaf((float)u.h[1], (float)wpk[K][1], w);
#endif
        DOT_STEP(0) DOT_STEP(1) DOT_STEP(2) DOT_STEP(3)
        DOT_STEP(4) DOT_STEP(5) DOT_STEP(6) DOT_STEP(7)
#undef DOT_STEP
#undef DOT_BODY

        int wi = __float_as_int(w);
        float w0 = __int_as_float(__builtin_amdgcn_ds_bpermute(bp0, wi));
        float w1 = __int_as_float(__builtin_amdgcn_ds_bpermute(bp1, wi));
        if (valid[j] && t < 8) {
            __half2 hv = __floats2half2_rn(w0, w1);
            unsafeAtomicAdd(S + (size_t)r[j] * 8 + t, hv);
        }
    }
}

__global__ __launch_bounds__(256) void epilogue_kernel(
    const _Float16* __restrict__ S, const float* __restrict__ right,
    const float* __restrict__ Wp, const float* __restrict__ bp,
    const float* __restrict__ Wo1, const float* __restrict__ bo1,
    const float* __restrict__ Wo2, const float* __restrict__ bo2,
    float* __restrict__ out, int N) {
    __shared__ float sWp[256], sWo2[256], sWo1[512];
    __shared__ float sbp[16], sbo1[16], sbo2[16];
    for (int i = threadIdx.x; i < 256; i += blockDim.x) {
        sWp[i] = Wp[i]; sWo2[i] = Wo2[i];
    }
    for (int i = threadIdx.x; i < 512; i += blockDim.x) sWo1[i] = Wo1[i];
    if (threadIdx.x < 16) {
        sbp[threadIdx.x] = bp[threadIdx.x];
        sbo1[threadIdx.x] = bo1[threadIdx.x];
        sbo2[threadIdx.x] = bo2[threadIdx.x];
    }
    __syncthreads();

    int n = blockIdx.x * blockDim.x + threadIdx.x;
    if (n >= N) return;

    float ra[EMB];
    {
        const half8* sp = (const half8*)(S + (size_t)n * EMB);
        half8 a0 = sp[0], a1 = sp[1];
#pragma unroll
        for (int k = 0; k < 8; ++k) ra[k] = fmaxf((float)a0[k], 0.0f);
#pragma unroll
        for (int k = 0; k < 8; ++k) ra[8 + k] = fmaxf((float)a1[k], 0.0f);
    }

    float p[EMB];
#pragma unroll
    for (int j = 0; j < EMB; ++j) {
        float a = sbp[j];
#pragma unroll
        for (int k = 0; k < EMB; ++k) a = fmaf(sWp[j * EMB + k], ra[k], a);
        p[j] = a;
    }

    float rf[EMB];
    {
        const float4* rp = (const float4*)(right + (size_t)n * EMB);
        float4 a0 = rp[0], a1 = rp[1], a2 = rp[2], a3 = rp[3];
        rf[0] = a0.x; rf[1] = a0.y; rf[2] = a0.z; rf[3] = a0.w;
        rf[4] = a1.x; rf[5] = a1.y; rf[6] = a1.z; rf[7] = a1.w;
        rf[8] = a2.x; rf[9] = a2.y; rf[10] = a2.z; rf[11] = a2.w;
        rf[12] = a3.x; rf[13] = a3.y; rf[14] = a3.z; rf[15] = a3.w;
    }

    float h[EMB];
#pragma unroll
    for (int j = 0; j < EMB; ++j) {
        float a = sbo1[j];
#pragma unroll
        for (int k = 0; k < EMB; ++k) a = fmaf(sWo1[j * 32 + k], p[k], a);
#pragma unroll
        for (int k = 0; k < EMB; ++k) a = fmaf(sWo1[j * 32 + 16 + k], rf[k], a);
        h[j] = fmaxf(a, 0.0f);
    }

    float o[EMB];
#pragma unroll
    for (int j = 0; j < EMB; ++j) {
        float a = sbo2[j];
#pragma unroll
        for (int k = 0; k < EMB; ++k) a = fmaf(sWo2[j * EMB + k], h[k], a);
        o[j] = a;
    }

    float4* op = (float4*)(out + (size_t)n * EMB);
    op[0] = make_float4(o[0], o[1], o[2], o[3]);
    op[1] = make_float4(o[4], o[5], o[6], o[7]);
    op[2] = make_float4(o[8], o[9], o[10], o[11]);
    op[3] = make_float4(o[12], o[13], o[14], o[15]);
}

// ---------------------------------------------------------------------------
extern "C" void kernel_launch(void* const* d_in, const int* in_sizes, int n_in,
                              void* d_out, int out_size, void* d_ws, size_t ws_size,
                              hipStream_t stream) {
    const float* left  = (const float*)d_in[0];
    const float* ef    = (const float*)d_in[1];
    const float* right = (const float*)d_in[2];
    const int*   eidx  = (const int*)d_in[3];
    const float* W_left  = (const float*)d_in[4];
    const float* b_left  = (const float*)d_in[5];
    const float* W_edge  = (const float*)d_in[6];
    const float* W_right = (const float*)d_in[7];
    const float* W_final = (const float*)d_in[8];
    const float* b_final = (const float*)d_in[9];
    const float* W_post  = (const float*)d_in[10];
    const float* b_post  = (const float*)d_in[11];
    const float* W_out1  = (const float*)d_in[12];
    const float* b_out1  = (const float*)d_in[13];
    const float* W_out2  = (const float*)d_in[14];
    const float* b_out2  = (const float*)d_in[15];

    const int NL = in_sizes[0] / EMB;
    const int NR = in_sizes[2] / EMB;
    const int E  = in_sizes[1];

    // Workspace: TL16 | TR16 | S (fp16)
    size_t tl_b = (size_t)NL * EMB * 2;
    size_t tr_b = (size_t)NR * EMB * 2;
    char* ws = (char*)d_ws;
    _Float16* TL = (_Float16*)ws;
    _Float16* TR = (_Float16*)(ws + tl_b);
    _Float16* S16 = (_Float16*)(ws + tl_b + tr_b);

    // ---- Preferred path: one cooperative kernel (no memset, no gaps) -----
    FArgs args;
    args.left = left; args.ef = ef; args.right = right; args.idx = eidx;
    args.Wl = W_left; args.bl = b_left; args.Wedge = W_edge; args.Wr = W_right;
    args.Wf = W_final; args.bf = b_final; args.Wp = W_post; args.bp = b_post;
    args.Wo1 = W_out1; args.bo1 = b_out1; args.Wo2 = W_out2; args.bo2 = b_out2;
    args.TL = TL; args.TR = TR; args.S16 = S16; args.out = (float*)d_out;
    args.NL = NL; args.NR = NR; args.E = E;
    args.G = (E + FEPT - 1) / FEPT;

    int maxB = 0;
    hipError_t qe = hipOccupancyMaxActiveBlocksPerMultiprocessor(
        &maxB, (const void*)fused_kernel, 256, 0);
    if (qe != hipSuccess || maxB < 1) maxB = 3;
    if (maxB > 8) maxB = 8;
    int blocks = 256 * maxB;   // MI355X: 256 CUs, all blocks co-resident

    void* kparams[] = {(void*)&args};
    hipError_t le = hipLaunchCooperativeKernel(
        (const void*)fused_kernel, dim3(blocks), dim3(256), kparams, 0, stream);

    if (le == hipSuccess) return;

    // ---- Fallback: proven R7 4-kernel sequence ---------------------------
    (void)hipMemsetAsync(S16, 0, (size_t)NR * EMB * 2, stream);

    node_transform2_kernel<<<(NL + NR + 255) / 256, 256, 0, stream>>>(
        left, right, W_left, b_left, W_right, TL, TR, NL, NR);

    {
        int G = (E + EPT - 1) / EPT;
        long long threads = (long long)G * 16;
        int nblocks = (int)((threads + 255) / 256);
        edge_scatter_kernel<<<nblocks, 256, 0, stream>>>(
            eidx, ef, TL, TR, W_edge, W_final, b_final, (__half2*)S16, E, G);
    }

    epilogue_kernel<<<(NR + 255) / 256, 256, 0, stream>>>(
        S16, right, W_post, b_post, W_out1, b_out1, W_out2, b_out2,
        (float*)d_out, NR);
}